// Round 9
// baseline (220.424 us; speedup 1.0000x reference)
//
#include <hip/hip_runtime.h>
#include <stdint.h>

#define DH 128   // D_IN == H == 128
#define NB 30    // num bases
#define NR 8     // num relations

typedef short bf16x8 __attribute__((ext_vector_type(8)));   // 8 bf16 = 4 VGPRs
typedef float f32x4 __attribute__((ext_vector_type(4)));
typedef float f32x2 __attribute__((ext_vector_type(2)));

static __device__ __forceinline__ unsigned short f2bf(float f) {
    unsigned u = __float_as_uint(f);
    u += 0x7fffu + ((u >> 16) & 1u);   // round-to-nearest-even
    return (unsigned short)(u >> 16);
}
static __device__ __forceinline__ float bflo(unsigned u) { return __uint_as_float(u << 16); }
static __device__ __forceinline__ float bfhi(unsigned u) { return __uint_as_float(u & 0xffff0000u); }

// K-dim storage permutation for gemm1 outputs (xw8/hb/hbf):
// position p within a node's 128 values holds true dim  dim(p) = (p&7)*16 + (p>>3).
// This is exactly the MFMA C-fragment order, so gemm1's epilogue stores straight
// from acc registers (no LDS repack). agg1 is elementwise (layout-agnostic);
// gemm2d compensates by loading W_rel/W_root2 with K-rows permuted by dim(p).
//
// Second layer uses linearity of segment-sum:  nbr@Wrel = segsum(h@Wrel).
// k_gemm2d: hw = bf16(h@Wrel), hro = bf16(h@Wroot2 + bias2), TRUE column order
// (LDS-repack epilogue). k_aggout: out = segsum(hw) + hro, coalesced float4.
// This deletes the nbrbf buffer (20.5MB w+r) and halves gemm2's A-staging.
//
// SPILL RULE (r1/r2/r7, 3x measured): any register array that must stay live
// across a barrier/MFMA region spills to scratch (+100-190MB HBM round-trips)
// even when VGPR_Count looks low. Tiles live in LDS; only acc lives in regs.

// ---------- merged weight-prep + edge histogram ----------
__global__ __launch_bounds__(256) void k_prephist(const float* __restrict__ comp,
                                                  const float* __restrict__ basis,
                                                  const float* __restrict__ root,
                                                  const float* __restrict__ wrel,
                                                  const float* __restrict__ wroot2,
                                                  unsigned short* __restrict__ wallT,
                                                  unsigned short* __restrict__ WT2,
                                                  const int* __restrict__ dstA, int E,
                                                  int* __restrict__ deg, int histB) {
    int b = blockIdx.x;
    int tid = threadIdx.x;
    if (b < histB) {
        int e = b * 256 + tid;
        if (e < E) atomicAdd(&deg[dstA[e]], 1);
        return;
    }
    int unit = (b - histB) * 2 + (tid >> 7);   // 0..1407 = y*128 + i
    int o = tid & 127;
    int i = unit & 127;
    int y = unit >> 7;                          // 0..10
    if (y < NR) {
        float s = 0.f;
        #pragma unroll
        for (int bb = 0; bb < NB; ++bb)
            s += comp[y * NB + bb] * basis[((size_t)bb * DH + i) * DH + o];
        wallT[((size_t)y * DH + o) * DH + i] = f2bf(s);
    } else if (y == NR) {
        wallT[((size_t)NR * DH + o) * DH + i] = f2bf(root[i * DH + o]);
    } else {
        const float* W = (y == NR + 2) ? wroot2 : wrel;
        int id = (i & 7) * 16 + (i >> 3);       // permute K-rows to match pi-layout
        WT2[((size_t)(y - NR - 1) * DH + o) * DH + i] = f2bf(W[(size_t)id * DH + o]);
    }
}

// ---------- single-pass scan: 4 elems/thread -> 10 blocks, lookback chain <=9 ----------
__global__ __launch_bounds__(1024) void k_scan(const int* __restrict__ deg, int n, int total_n,
                                               int* __restrict__ offsets,
                                               int* __restrict__ cursor,
                                               unsigned long long* __restrict__ st,
                                               int* __restrict__ ticket) {
    __shared__ int s[1024];
    __shared__ int bid_s, pre_s;
    const int tid = threadIdx.x;
    if (tid == 0) bid_s = atomicAdd(ticket, 1);
    __syncthreads();
    const int b = bid_s;
    const int base = b * 4096 + tid * 4;
    int v[4];
    #pragma unroll
    for (int j = 0; j < 4; ++j) {
        int i = base + j;
        v[j] = (i < n) ? deg[i] : 0;
    }
    int tsum = v[0] + v[1] + v[2] + v[3];
    s[tid] = tsum;
    __syncthreads();
    for (int off = 1; off < 1024; off <<= 1) {
        int t = (tid >= off) ? s[tid - off] : 0;
        __syncthreads();
        s[tid] += t;
        __syncthreads();
    }
    if (tid == 0) {
        int total = s[1023];
        atomicExch(&st[b], (1ULL << 62) | (unsigned long long)(unsigned)total);
        long long pre = 0;
        int t = b - 1;
        while (t >= 0) {
            unsigned long long w;
            do { w = atomicAdd(&st[t], 0ULL); } while (w == 0ULL);
            pre += (long long)(w & 0x3FFFFFFFFFFFFFFFULL);
            if ((w >> 62) == 2ULL) break;
            --t;
        }
        atomicExch(&st[b], (2ULL << 62) | (unsigned long long)(pre + total));
        pre_s = (int)pre;
    }
    __syncthreads();
    int run = pre_s + s[tid] - tsum;   // exclusive prefix at base
    #pragma unroll
    for (int j = 0; j < 4; ++j) {
        int i = base + j;
        if (i < total_n) offsets[i] = run;
        if (i < n) cursor[i] = run;
        run += v[j];
    }
}

// ---------- fused MFMA GEMM1 + scatter (role-interleaved) — r6/r8 verified body ----------
__global__ __launch_bounds__(256, 3) void k_gemm1s(const float* __restrict__ x,
                                                   const unsigned short* __restrict__ wallT,
                                                   const float* __restrict__ bias1,
                                                   int Nn,
                                                   unsigned* __restrict__ xw8,
                                                   unsigned short* __restrict__ hb,
                                                   const int* __restrict__ src,
                                                   const int* __restrict__ dstA,
                                                   const int* __restrict__ etype, int E,
                                                   int* __restrict__ cursor,
                                                   unsigned* __restrict__ sorted,
                                                   int scatB, int gx) {
    __shared__ __align__(16) unsigned short As[64][136];   // A-tile (staged once per block)
    __shared__ __align__(16) unsigned short Bs[128][136];  // B-tile staging
    const int tid = threadIdx.x;
    const int b = blockIdx.x;

    // role interleave: b < 2*scatB -> odd = scatter, even = gemm; rest = gemm
    const bool is_scat = (b < 2 * scatB) && (b & 1);

    if (is_scat) {                        // ---- scatter role ----
        const int sidx = b >> 1;          // 0..scatB-1
        const int stride = scatB * 256;
        for (int e = sidx * 256 + tid; e < E; e += stride) {
            int d = dstA[e];
            int pos = atomicAdd(&cursor[d], 1);
            sorted[pos] = (unsigned)src[e] | ((unsigned)etype[e] << 17);  // src<2^17, type<8
        }
        return;
    }

    const int bg = (b < 2 * scatB) ? (b >> 1) : (b - scatB);   // 0..gemmB-1
    const int wave = tid >> 6, lane = tid & 63;
    const int g = bg / gx;
    const int rowbase = (bg % gx) * 64;
    const int lq = lane >> 4, lr = lane & 15;

    // stage A once: fp32 -> bf16 on the fly (64 rows x 128 cols)
    #pragma unroll
    for (int it = 0; it < 4; ++it) {
        int c = it * 256 + tid;
        int row = c >> 4, col = c & 15;
        int rg = rowbase + row; if (rg >= Nn) rg = Nn - 1;
        float4 v0 = *(const float4*)&x[(size_t)rg * DH + col * 8];
        float4 v1 = *(const float4*)&x[(size_t)rg * DH + col * 8 + 4];
        uint4 u;
        u.x = (unsigned)f2bf(v0.x) | ((unsigned)f2bf(v0.y) << 16);
        u.y = (unsigned)f2bf(v0.z) | ((unsigned)f2bf(v0.w) << 16);
        u.z = (unsigned)f2bf(v1.x) | ((unsigned)f2bf(v1.y) << 16);
        u.w = (unsigned)f2bf(v1.z) | ((unsigned)f2bf(v1.w) << 16);
        *(uint4*)&As[row][col * 8] = u;
    }

    for (int rr = 0; rr < 3; ++rr) {
        const int r = g * 3 + rr;
        const unsigned short* WT = wallT + (size_t)r * DH * DH;
        if (rr) __syncthreads();            // prior MFMA reads of Bs done before restage
        #pragma unroll
        for (int it = 0; it < 8; ++it) {
            int c = it * 256 + tid;
            int row = c >> 4, col = c & 15;
            *(uint4*)&Bs[row][col * 8] = *(const uint4*)&WT[(size_t)row * DH + col * 8];
        }
        __syncthreads();                    // also covers As on first iter

        f32x4 acc[8];
        #pragma unroll
        for (int nt = 0; nt < 8; ++nt) acc[nt] = (f32x4)0.f;

        #pragma unroll
        for (int ks = 0; ks < 4; ++ks) {
            const int ko = ks * 32 + lq * 8;
            bf16x8 a0 = *(const bf16x8*)&As[wave * 16 + lr][ko];
            #pragma unroll
            for (int nt = 0; nt < 8; ++nt) {
                bf16x8 bb = *(const bf16x8*)&Bs[nt * 16 + lr][ko];
                acc[nt] = __builtin_amdgcn_mfma_f32_16x16x32_bf16(a0, bb, acc[nt], 0, 0, 0);
            }
        }
        // direct-from-acc epilogue (pi-layout), no LDS, no extra barrier:
        // lane holds C[m][nt*16+lr] for m = rowbase + wave*16 + lq*4 + reg
        if (r < NR) {
            unsigned* dst = xw8 + ((size_t)r * Nn + rowbase) * (DH / 4);
            #pragma unroll
            for (int reg = 0; reg < 4; ++reg) {
                int m = wave * 16 + lq * 4 + reg;   // local row
                if (rowbase + m < Nn) {
                    uint2 o;
                    o.x = __builtin_amdgcn_cvt_pk_fp8_f32(acc[0][reg], acc[1][reg], 0, false);
                    o.x = __builtin_amdgcn_cvt_pk_fp8_f32(acc[2][reg], acc[3][reg], o.x, true);
                    o.y = __builtin_amdgcn_cvt_pk_fp8_f32(acc[4][reg], acc[5][reg], 0, false);
                    o.y = __builtin_amdgcn_cvt_pk_fp8_f32(acc[6][reg], acc[7][reg], o.y, true);
                    *(uint2*)&dst[(size_t)m * (DH / 4) + lr * 2] = o;
                }
            }
        } else {
            float bv[8];
            #pragma unroll
            for (int nt = 0; nt < 8; ++nt) bv[nt] = bias1[nt * 16 + lr];
            #pragma unroll
            for (int reg = 0; reg < 4; ++reg) {
                int m = rowbase + wave * 16 + lq * 4 + reg;
                if (m < Nn) {
                    uint4 u;
                    u.x = (unsigned)f2bf(acc[0][reg] + bv[0]) | ((unsigned)f2bf(acc[1][reg] + bv[1]) << 16);
                    u.y = (unsigned)f2bf(acc[2][reg] + bv[2]) | ((unsigned)f2bf(acc[3][reg] + bv[3]) << 16);
                    u.z = (unsigned)f2bf(acc[4][reg] + bv[4]) | ((unsigned)f2bf(acc[5][reg] + bv[5]) << 16);
                    u.w = (unsigned)f2bf(acc[6][reg] + bv[6]) | ((unsigned)f2bf(acc[7][reg] + bv[7]) << 16);
                    *(uint4*)&hb[(size_t)m * DH + lr * 8] = u;
                }
            }
        }
    }
}

// ---------- pass-1 aggregation: one wave per dst, fp8 gather, 2 edges/step x8 ----------
// hbf[dst] = bf16( hb[dst] + (1/deg) * sum_e xw8[type_e][src_e] )   (pi-layout)
__global__ __launch_bounds__(256) void k_agg1(const int* __restrict__ offsets,
                                              const unsigned* __restrict__ sorted,
                                              const unsigned* __restrict__ xw8,
                                              const unsigned* __restrict__ hb32,
                                              int Nn, unsigned* __restrict__ hbf) {
    int w = (blockIdx.x * blockDim.x + threadIdx.x) >> 6;
    if (w >= Nn) return;
    int lane = threadIdx.x & 63;
    int half = lane >> 5, sub = lane & 31;
    int s = offsets[w], e = offsets[w + 1];
    float a0 = 0.f, a1 = 0.f, a2 = 0.f, a3 = 0.f;
    int p = s;
    for (; p + 16 <= e; p += 16) {            // unmasked main loop
        unsigned pk[8];
        #pragma unroll
        for (int j = 0; j < 8; ++j) pk[j] = sorted[p + 2 * j + half];
        unsigned u[8];
        #pragma unroll
        for (int j = 0; j < 8; ++j)
            u[j] = xw8[((size_t)(pk[j] >> 17) * Nn + (pk[j] & 0x1FFFFu)) * 32 + sub];
        #pragma unroll
        for (int j = 0; j < 8; ++j) {
            f32x2 lo = __builtin_amdgcn_cvt_pk_f32_fp8(u[j], false);
            f32x2 hi = __builtin_amdgcn_cvt_pk_f32_fp8(u[j], true);
            a0 += lo.x; a1 += lo.y; a2 += hi.x; a3 += hi.y;
        }
    }
    if (p < e) {                              // masked tail
        unsigned pk[8]; float m[8];
        #pragma unroll
        for (int j = 0; j < 8; ++j) {
            int q = p + 2 * j + half; bool v = q < e;
            pk[j] = sorted[v ? q : e - 1];
            m[j] = v ? 1.f : 0.f;
        }
        unsigned u[8];
        #pragma unroll
        for (int j = 0; j < 8; ++j)
            u[j] = xw8[((size_t)(pk[j] >> 17) * Nn + (pk[j] & 0x1FFFFu)) * 32 + sub];
        #pragma unroll
        for (int j = 0; j < 8; ++j) {
            f32x2 lo = __builtin_amdgcn_cvt_pk_f32_fp8(u[j], false);
            f32x2 hi = __builtin_amdgcn_cvt_pk_f32_fp8(u[j], true);
            a0 = fmaf(m[j], lo.x, a0);
            a1 = fmaf(m[j], lo.y, a1);
            a2 = fmaf(m[j], hi.x, a2);
            a3 = fmaf(m[j], hi.y, a3);
        }
    }
    a0 += __shfl_xor(a0, 32, 64);
    a1 += __shfl_xor(a1, 32, 64);
    a2 += __shfl_xor(a2, 32, 64);
    a3 += __shfl_xor(a3, 32, 64);
    if (half == 0) {
        float invd = 1.0f / fmaxf((float)(e - s), 1.0f);
        uint2 hv = *(const uint2*)&hb32[(size_t)w * 64 + sub * 2];
        float h0 = bflo(hv.x) + a0 * invd;
        float h1 = bfhi(hv.x) + a1 * invd;
        float h2 = bflo(hv.y) + a2 * invd;
        float h3 = bfhi(hv.y) + a3 * invd;
        uint2 o;
        o.x = (unsigned)f2bf(h0) | ((unsigned)f2bf(h1) << 16);
        o.y = (unsigned)f2bf(h2) | ((unsigned)f2bf(h3) << 16);
        *(uint2*)&hbf[(size_t)w * 64 + sub * 2] = o;
    }
}

// ---------- dual-B GEMM: hw = bf16(h@Wrel), hro = bf16(h@Wroot2 + bias2) ----------
// A = hbf (pi-layout) staged ONCE; WT2 K-rows pre-permuted -> outputs in TRUE
// column order via the r0-verified LDS-repack epilogue (cheap: 1250 instances).
__global__ __launch_bounds__(256, 3) void k_gemm2d(const unsigned short* __restrict__ hbf,
                                                   const unsigned short* __restrict__ WT2,
                                                   const float* __restrict__ bias2,
                                                   int Nn,
                                                   unsigned short* __restrict__ hw,
                                                   unsigned short* __restrict__ hro) {
    __shared__ __align__(16) unsigned short As[64][136];
    __shared__ __align__(16) unsigned short Bs[128][136];
    const int tid = threadIdx.x;
    const int wave = tid >> 6, lane = tid & 63;
    const int rowbase = blockIdx.x * 64;
    const int lq = lane >> 4, lr = lane & 15;

    #pragma unroll
    for (int it = 0; it < 4; ++it) {
        int c = it * 256 + tid;
        int row = c >> 4, col = c & 15;
        int rg = rowbase + row; if (rg >= Nn) rg = Nn - 1;
        *(uint4*)&As[row][col * 8] = *(const uint4*)&hbf[(size_t)rg * DH + col * 8];
    }

    for (int ph = 0; ph < 2; ++ph) {
        const unsigned short* WT = WT2 + (size_t)ph * DH * DH;
        if (ph) __syncthreads();            // prior store reads of Bs done
        #pragma unroll
        for (int it = 0; it < 8; ++it) {
            int c = it * 256 + tid;
            int row = c >> 4, col = c & 15;
            *(uint4*)&Bs[row][col * 8] = *(const uint4*)&WT[(size_t)row * DH + col * 8];
        }
        __syncthreads();                    // covers As on first iter

        f32x4 acc[8];
        #pragma unroll
        for (int nt = 0; nt < 8; ++nt) acc[nt] = (f32x4)0.f;

        #pragma unroll
        for (int ks = 0; ks < 4; ++ks) {
            const int ko = ks * 32 + lq * 8;
            bf16x8 a0 = *(const bf16x8*)&As[wave * 16 + lr][ko];
            #pragma unroll
            for (int nt = 0; nt < 8; ++nt) {
                bf16x8 bb = *(const bf16x8*)&Bs[nt * 16 + lr][ko];
                acc[nt] = __builtin_amdgcn_mfma_f32_16x16x32_bf16(a0, bb, acc[nt], 0, 0, 0);
            }
        }
        __syncthreads();                    // MFMA reads of Bs done

        // repack C-layout -> TRUE-order bf16 rows in Bs[0..63]
        float bv[8];
        #pragma unroll
        for (int nt = 0; nt < 8; ++nt) bv[nt] = ph ? bias2[nt * 16 + lr] : 0.f;
        #pragma unroll
        for (int nt = 0; nt < 8; ++nt)
            #pragma unroll
            for (int reg = 0; reg < 4; ++reg) {
                int ml = wave * 16 + lq * 4 + reg;   // own slab only
                Bs[ml][nt * 16 + lr] = f2bf(acc[nt][reg] + bv[nt]);
            }
        __syncthreads();

        unsigned short* dst = ph ? hro : hw;
        #pragma unroll
        for (int it = 0; it < 4; ++it) {
            int c = it * 256 + tid;
            int row = c >> 4, col = c & 15;
            if (rowbase + row < Nn)
                *(uint4*)&dst[(size_t)(rowbase + row) * DH + col * 8] = *(uint4*)&Bs[row][col * 8];
        }
    }
}

// ---------- final: out[w] = segsum(hw[src]) + hro[w]  (full occupancy, no LDS) ----------
__global__ __launch_bounds__(256) void k_aggout(const int* __restrict__ offsets,
                                                const unsigned* __restrict__ sorted,
                                                const uint2* __restrict__ hw2,
                                                const uint2* __restrict__ hro2,
                                                int Nn, float* __restrict__ out) {
    int w = (blockIdx.x * blockDim.x + threadIdx.x) >> 6;
    if (w >= Nn) return;
    int lane = threadIdx.x & 63;
    int half = lane >> 5, sub = lane & 31;
    int s = offsets[w], e = offsets[w + 1];
    float a0 = 0.f, a1 = 0.f, a2 = 0.f, a3 = 0.f;
    int p = s;
    for (; p + 16 <= e; p += 16) {
        unsigned pk[8];
        #pragma unroll
        for (int j = 0; j < 8; ++j) pk[j] = sorted[p + 2 * j + half];
        uint2 u[8];
        #pragma unroll
        for (int j = 0; j < 8; ++j)
            u[j] = hw2[(size_t)(pk[j] & 0x1FFFFu) * 32 + sub];
        #pragma unroll
        for (int j = 0; j < 8; ++j) {
            a0 += bflo(u[j].x); a1 += bfhi(u[j].x);
            a2 += bflo(u[j].y); a3 += bfhi(u[j].y);
        }
    }
    if (p < e) {
        unsigned pk[8]; float m[8];
        #pragma unroll
        for (int j = 0; j < 8; ++j) {
            int q = p + 2 * j + half; bool v = q < e;
            pk[j] = sorted[v ? q : e - 1];
            m[j] = v ? 1.f : 0.f;
        }
        uint2 u[8];
        #pragma unroll
        for (int j = 0; j < 8; ++j)
            u[j] = hw2[(size_t)(pk[j] & 0x1FFFFu) * 32 + sub];
        #pragma unroll
        for (int j = 0; j < 8; ++j) {
            a0 = fmaf(m[j], bflo(u[j].x), a0);
            a1 = fmaf(m[j], bfhi(u[j].x), a1);
            a2 = fmaf(m[j], bflo(u[j].y), a2);
            a3 = fmaf(m[j], bfhi(u[j].y), a3);
        }
    }
    a0 += __shfl_xor(a0, 32, 64);
    a1 += __shfl_xor(a1, 32, 64);
    a2 += __shfl_xor(a2, 32, 64);
    a3 += __shfl_xor(a3, 32, 64);
    if (half == 0) {
        uint2 hv = hro2[(size_t)w * 32 + sub];
        float4 o;
        o.x = a0 + bflo(hv.x);
        o.y = a1 + bfhi(hv.x);
        o.z = a2 + bflo(hv.y);
        o.w = a3 + bfhi(hv.y);
        *(float4*)&out[(size_t)w * DH + sub * 4] = o;
    }
}

extern "C" void kernel_launch(void* const* d_in, const int* in_sizes, int n_in,
                              void* d_out, int out_size, void* d_ws, size_t ws_size,
                              hipStream_t stream) {
    const float* x      = (const float*)d_in[0];
    const int*   eidx   = (const int*)d_in[1];
    // d_in[2] = edge_norm: unused by the reference computation
    const int*   etype  = (const int*)d_in[3];
    const float* basis  = (const float*)d_in[4];
    const float* comp   = (const float*)d_in[5];
    const float* root   = (const float*)d_in[6];
    const float* bias1  = (const float*)d_in[7];
    const float* wrel   = (const float*)d_in[8];
    const float* wroot2 = (const float*)d_in[9];
    const float* bias2  = (const float*)d_in[10];
    float* out = (float*)d_out;

    const int N = in_sizes[0] / DH;    // 40000
    const int E = in_sizes[3];         // 640000
    const int* srcA = eidx;
    const int* dstA = eidx + E;

    char* ws = (char*)d_ws;
    size_t off = 0;
    auto alloc = [&](size_t bytes) -> void* {
        void* p = (void*)(ws + off);
        off += (bytes + 255) & ~(size_t)255;
        return p;
    };
    // deg, st, ticket contiguous -> zeroed by one memset (cursor written by k_scan)
    int* deg           = (int*)alloc((size_t)N * 4);          // N*4 multiple of 256
    unsigned long long* st = (unsigned long long*)alloc(64 * 8);   // 512 B
    int* ticket        = (int*)alloc(256);
    int* cursor        = (int*)alloc((size_t)N * 4);
    int* offsets       = (int*)alloc((size_t)(N + 1) * 4);
    unsigned* sorted   = (unsigned*)alloc((size_t)E * 4);
    unsigned short* wallT = (unsigned short*)alloc((size_t)(NR + 1) * DH * DH * 2);
    unsigned short* WT2   = (unsigned short*)alloc((size_t)2 * DH * DH * 2);
    unsigned* xw8      = (unsigned*)alloc((size_t)NR * N * DH);       // fp8 e4m3
    unsigned short* hb = (unsigned short*)alloc((size_t)N * DH * 2);
    unsigned* hbf      = (unsigned*)alloc((size_t)N * (DH / 2) * 4);  // h, pi-layout bf16
    unsigned short* hw  = (unsigned short*)alloc((size_t)N * DH * 2); // h@Wrel, true order
    unsigned short* hro = (unsigned short*)alloc((size_t)N * DH * 2); // h@Wroot2+b2, true order
    (void)ws_size; (void)n_in; (void)out_size;

    hipMemsetAsync(deg, 0, (size_t)N * 4 + 768, stream);  // deg + st + ticket

    const int histB = (E + 255) / 256;              // 2500
    k_prephist<<<histB + 704, 256, 0, stream>>>(comp, basis, root, wrel, wroot2,
                                                wallT, WT2, dstA, E, deg, histB);

    const int totn = N + 1;
    const int nsb = (totn + 4095) / 4096;           // 10
    k_scan<<<nsb, 1024, 0, stream>>>(deg, N, totn, offsets, cursor, st, ticket);

    const int gx = (N + 63) / 64;                   // 625 (64-row tiles)
    const int gemmB = gx * 3;                       // 1875 (3 relations/block)
    const int scatB = 1280;                         // grid-stride scatter blocks (interleaved)
    k_gemm1s<<<scatB + gemmB, 256, 0, stream>>>(x, wallT, bias1, N, xw8, hb,
                                                srcA, dstA, etype, E, cursor, sorted,
                                                scatB, gx);

    k_agg1<<<(N * 64) / 256, 256, 0, stream>>>(offsets, sorted, xw8,
                                               (const unsigned*)hb, N, hbf);
    k_gemm2d<<<gx, 256, 0, stream>>>((const unsigned short*)hbf, WT2, bias2, N, hw, hro);
    k_aggout<<<(N * 64) / 256, 256, 0, stream>>>(offsets, sorted, (const uint2*)hw,
                                                 (const uint2*)hro, N, out);
}

// Round 10
// 219.084 us; speedup vs baseline: 1.0061x; 1.0061x over previous
//
#include <hip/hip_runtime.h>
#include <stdint.h>

#define DH 128   // D_IN == H == 128
#define NB 30    // num bases
#define NR 8     // num relations

typedef short bf16x8 __attribute__((ext_vector_type(8)));   // 8 bf16 = 4 VGPRs
typedef float f32x4 __attribute__((ext_vector_type(4)));
typedef float f32x2 __attribute__((ext_vector_type(2)));

static __device__ __forceinline__ unsigned short f2bf(float f) {
    unsigned u = __float_as_uint(f);
    u += 0x7fffu + ((u >> 16) & 1u);   // round-to-nearest-even
    return (unsigned short)(u >> 16);
}
static __device__ __forceinline__ float bflo(unsigned u) { return __uint_as_float(u << 16); }
static __device__ __forceinline__ float bfhi(unsigned u) { return __uint_as_float(u & 0xffff0000u); }

// K-dim storage permutation for gemm1 outputs (xw8/hb/hbf):
// position p within a node's 128 values holds true dim  dim(p) = (p&7)*16 + (p>>3).
// gemm1 epilogue stores straight from acc (no LDS repack); agg1 is layout-agnostic;
// gemm2d compensates by loading W_rel/W_root2 with K-rows permuted by dim(p).
//
// Second layer uses linearity of segment-sum:  nbr@Wrel = segsum(h@Wrel).
//
// SPILL RULE (r1/r2/r7, 3x measured): any register array that must stay live
// across a barrier/MFMA region spills to scratch (+100-190MB HBM round-trips)
// even when VGPR_Count looks low. Tiles live in LDS; only acc lives in regs.
//
// RANK TRICK (r10): the histogram atomicAdd's return value IS the edge's rank
// within its dst segment -> store it, and the scatter phase needs NO atomics:
// sorted[offsets[d] + rank[e]].

// ---------- merged weight-prep + edge histogram (+rank) ----------
__global__ __launch_bounds__(256) void k_prephist(const float* __restrict__ comp,
                                                  const float* __restrict__ basis,
                                                  const float* __restrict__ root,
                                                  const float* __restrict__ wrel,
                                                  const float* __restrict__ wroot2,
                                                  unsigned short* __restrict__ wallT,
                                                  unsigned short* __restrict__ WT2,
                                                  const int* __restrict__ dstA, int E,
                                                  int* __restrict__ deg,
                                                  int* __restrict__ rank, int histB) {
    int b = blockIdx.x;
    int tid = threadIdx.x;
    if (b < histB) {
        int e = b * 256 + tid;
        if (e < E) rank[e] = atomicAdd(&deg[dstA[e]], 1);
        return;
    }
    int unit = (b - histB) * 2 + (tid >> 7);   // 0..1407 = y*128 + i
    int o = tid & 127;
    int i = unit & 127;
    int y = unit >> 7;                          // 0..10
    if (y < NR) {
        float s = 0.f;
        #pragma unroll
        for (int bb = 0; bb < NB; ++bb)
            s += comp[y * NB + bb] * basis[((size_t)bb * DH + i) * DH + o];
        wallT[((size_t)y * DH + o) * DH + i] = f2bf(s);
    } else if (y == NR) {
        wallT[((size_t)NR * DH + o) * DH + i] = f2bf(root[i * DH + o]);
    } else {
        const float* W = (y == NR + 2) ? wroot2 : wrel;
        int id = (i & 7) * 16 + (i >> 3);       // permute K-rows to match pi-layout
        WT2[((size_t)(y - NR - 1) * DH + o) * DH + i] = f2bf(W[(size_t)id * DH + o]);
    }
}

// ---------- single-pass scan: 4 elems/thread -> 10 blocks, lookback chain <=9 ----------
__global__ __launch_bounds__(1024) void k_scan(const int* __restrict__ deg, int n, int total_n,
                                               int* __restrict__ offsets,
                                               unsigned long long* __restrict__ st,
                                               int* __restrict__ ticket) {
    __shared__ int s[1024];
    __shared__ int bid_s, pre_s;
    const int tid = threadIdx.x;
    if (tid == 0) bid_s = atomicAdd(ticket, 1);
    __syncthreads();
    const int b = bid_s;
    const int base = b * 4096 + tid * 4;
    int v[4];
    #pragma unroll
    for (int j = 0; j < 4; ++j) {
        int i = base + j;
        v[j] = (i < n) ? deg[i] : 0;
    }
    int tsum = v[0] + v[1] + v[2] + v[3];
    s[tid] = tsum;
    __syncthreads();
    for (int off = 1; off < 1024; off <<= 1) {
        int t = (tid >= off) ? s[tid - off] : 0;
        __syncthreads();
        s[tid] += t;
        __syncthreads();
    }
    if (tid == 0) {
        int total = s[1023];
        atomicExch(&st[b], (1ULL << 62) | (unsigned long long)(unsigned)total);
        long long pre = 0;
        int t = b - 1;
        while (t >= 0) {
            unsigned long long w;
            do { w = atomicAdd(&st[t], 0ULL); } while (w == 0ULL);
            pre += (long long)(w & 0x3FFFFFFFFFFFFFFFULL);
            if ((w >> 62) == 2ULL) break;
            --t;
        }
        atomicExch(&st[b], (2ULL << 62) | (unsigned long long)(pre + total));
        pre_s = (int)pre;
    }
    __syncthreads();
    int run = pre_s + s[tid] - tsum;   // exclusive prefix at base
    #pragma unroll
    for (int j = 0; j < 4; ++j) {
        int i = base + j;
        if (i < total_n) offsets[i] = run;
        run += v[j];
    }
}

// ---------- fused MFMA GEMM1 + scatter (512-thread blocks, role-interleaved) ----------
// 512 threads, 128-row A-tile, 8 waves: per-wave structure identical to the
// verified r8 body (16 rows x 128 cols, 9 ds_read_b128 : 8 MFMA per ks), but
// LDS = As[128]+Bs[128] = 69.6KB -> 2 blocks/CU x 8 waves = 16 waves/CU
// (vs 12 at 256-thr/52KB), and B-staging count halves (939 vs 1875).
// launch_bounds(512,4): VGPR cap 128; live state = acc 32 AGPR + ~68 VGPR ~ 100.
// Scatter role is ATOMIC-FREE via rank[] (pos = offsets[d] + rank[e]).
__global__ __launch_bounds__(512, 4) void k_gemm1s(const float* __restrict__ x,
                                                   const unsigned short* __restrict__ wallT,
                                                   const float* __restrict__ bias1,
                                                   int Nn,
                                                   unsigned* __restrict__ xw8,
                                                   unsigned short* __restrict__ hb,
                                                   const int* __restrict__ src,
                                                   const int* __restrict__ dstA,
                                                   const int* __restrict__ etype, int E,
                                                   const int* __restrict__ offsets,
                                                   const int* __restrict__ rank,
                                                   unsigned* __restrict__ sorted,
                                                   int scatB, int gx) {
    __shared__ __align__(16) unsigned short As[128][136];  // A-tile (staged once per block)
    __shared__ __align__(16) unsigned short Bs[128][136];  // B-tile staging
    const int tid = threadIdx.x;
    const int b = blockIdx.x;

    // role interleave: b < 2*scatB -> odd = scatter, even = gemm; rest = gemm
    const bool is_scat = (b < 2 * scatB) && (b & 1);

    if (is_scat) {                        // ---- scatter role (no atomics) ----
        const int sidx = b >> 1;          // 0..scatB-1
        const int stride = scatB * 512;
        for (int e = sidx * 512 + tid; e < E; e += stride) {
            int d = dstA[e];
            int pos = offsets[d] + rank[e];
            sorted[pos] = (unsigned)src[e] | ((unsigned)etype[e] << 17);  // src<2^17, type<8
        }
        return;
    }

    const int bg = (b < 2 * scatB) ? (b >> 1) : (b - scatB);   // 0..gemmB-1
    const int wave = tid >> 6, lane = tid & 63;                // wave 0..7
    const int g = bg / gx;
    const int rowbase = (bg % gx) * 128;
    const int lq = lane >> 4, lr = lane & 15;

    // stage A once: fp32 -> bf16 on the fly (128 rows x 128 cols)
    #pragma unroll
    for (int it = 0; it < 4; ++it) {
        int c = it * 512 + tid;
        int row = c >> 4, col = c & 15;
        int rg = rowbase + row; if (rg >= Nn) rg = Nn - 1;
        float4 v0 = *(const float4*)&x[(size_t)rg * DH + col * 8];
        float4 v1 = *(const float4*)&x[(size_t)rg * DH + col * 8 + 4];
        uint4 u;
        u.x = (unsigned)f2bf(v0.x) | ((unsigned)f2bf(v0.y) << 16);
        u.y = (unsigned)f2bf(v0.z) | ((unsigned)f2bf(v0.w) << 16);
        u.z = (unsigned)f2bf(v1.x) | ((unsigned)f2bf(v1.y) << 16);
        u.w = (unsigned)f2bf(v1.z) | ((unsigned)f2bf(v1.w) << 16);
        *(uint4*)&As[row][col * 8] = u;
    }

    for (int rr = 0; rr < 3; ++rr) {
        const int r = g * 3 + rr;
        const unsigned short* WT = wallT + (size_t)r * DH * DH;
        if (rr) __syncthreads();            // prior MFMA reads of Bs done before restage
        #pragma unroll
        for (int it = 0; it < 4; ++it) {
            int c = it * 512 + tid;
            int row = c >> 4, col = c & 15;
            *(uint4*)&Bs[row][col * 8] = *(const uint4*)&WT[(size_t)row * DH + col * 8];
        }
        __syncthreads();                    // also covers As on first iter

        f32x4 acc[8];
        #pragma unroll
        for (int nt = 0; nt < 8; ++nt) acc[nt] = (f32x4)0.f;

        #pragma unroll
        for (int ks = 0; ks < 4; ++ks) {
            const int ko = ks * 32 + lq * 8;
            bf16x8 a0 = *(const bf16x8*)&As[wave * 16 + lr][ko];
            #pragma unroll
            for (int nt = 0; nt < 8; ++nt) {
                bf16x8 bb = *(const bf16x8*)&Bs[nt * 16 + lr][ko];
                acc[nt] = __builtin_amdgcn_mfma_f32_16x16x32_bf16(a0, bb, acc[nt], 0, 0, 0);
            }
        }
        // direct-from-acc epilogue (pi-layout), no LDS, no extra barrier:
        // lane holds C[m][nt*16+lr] for m = rowbase + wave*16 + lq*4 + reg
        if (r < NR) {
            unsigned* dst = xw8 + ((size_t)r * Nn + rowbase) * (DH / 4);
            #pragma unroll
            for (int reg = 0; reg < 4; ++reg) {
                int m = wave * 16 + lq * 4 + reg;   // local row 0..127
                if (rowbase + m < Nn) {
                    uint2 o;
                    o.x = __builtin_amdgcn_cvt_pk_fp8_f32(acc[0][reg], acc[1][reg], 0, false);
                    o.x = __builtin_amdgcn_cvt_pk_fp8_f32(acc[2][reg], acc[3][reg], o.x, true);
                    o.y = __builtin_amdgcn_cvt_pk_fp8_f32(acc[4][reg], acc[5][reg], 0, false);
                    o.y = __builtin_amdgcn_cvt_pk_fp8_f32(acc[6][reg], acc[7][reg], o.y, true);
                    *(uint2*)&dst[(size_t)m * (DH / 4) + lr * 2] = o;
                }
            }
        } else {
            float bv[8];
            #pragma unroll
            for (int nt = 0; nt < 8; ++nt) bv[nt] = bias1[nt * 16 + lr];
            #pragma unroll
            for (int reg = 0; reg < 4; ++reg) {
                int m = rowbase + wave * 16 + lq * 4 + reg;
                if (m < Nn) {
                    uint4 u;
                    u.x = (unsigned)f2bf(acc[0][reg] + bv[0]) | ((unsigned)f2bf(acc[1][reg] + bv[1]) << 16);
                    u.y = (unsigned)f2bf(acc[2][reg] + bv[2]) | ((unsigned)f2bf(acc[3][reg] + bv[3]) << 16);
                    u.z = (unsigned)f2bf(acc[4][reg] + bv[4]) | ((unsigned)f2bf(acc[5][reg] + bv[5]) << 16);
                    u.w = (unsigned)f2bf(acc[6][reg] + bv[6]) | ((unsigned)f2bf(acc[7][reg] + bv[7]) << 16);
                    *(uint4*)&hb[(size_t)m * DH + lr * 8] = u;
                }
            }
        }
    }
}

// ---------- pass-1 aggregation: one wave per dst, fp8 gather, 2 edges/step x8 ----------
// hbf[dst] = bf16( hb[dst] + (1/deg) * sum_e xw8[type_e][src_e] )   (pi-layout)
__global__ __launch_bounds__(256) void k_agg1(const int* __restrict__ offsets,
                                              const unsigned* __restrict__ sorted,
                                              const unsigned* __restrict__ xw8,
                                              const unsigned* __restrict__ hb32,
                                              int Nn, unsigned* __restrict__ hbf) {
    int w = (blockIdx.x * blockDim.x + threadIdx.x) >> 6;
    if (w >= Nn) return;
    int lane = threadIdx.x & 63;
    int half = lane >> 5, sub = lane & 31;
    int s = offsets[w], e = offsets[w + 1];
    float a0 = 0.f, a1 = 0.f, a2 = 0.f, a3 = 0.f;
    int p = s;
    for (; p + 16 <= e; p += 16) {            // unmasked main loop
        unsigned pk[8];
        #pragma unroll
        for (int j = 0; j < 8; ++j) pk[j] = sorted[p + 2 * j + half];
        unsigned u[8];
        #pragma unroll
        for (int j = 0; j < 8; ++j)
            u[j] = xw8[((size_t)(pk[j] >> 17) * Nn + (pk[j] & 0x1FFFFu)) * 32 + sub];
        #pragma unroll
        for (int j = 0; j < 8; ++j) {
            f32x2 lo = __builtin_amdgcn_cvt_pk_f32_fp8(u[j], false);
            f32x2 hi = __builtin_amdgcn_cvt_pk_f32_fp8(u[j], true);
            a0 += lo.x; a1 += lo.y; a2 += hi.x; a3 += hi.y;
        }
    }
    if (p < e) {                              // masked tail
        unsigned pk[8]; float m[8];
        #pragma unroll
        for (int j = 0; j < 8; ++j) {
            int q = p + 2 * j + half; bool v = q < e;
            pk[j] = sorted[v ? q : e - 1];
            m[j] = v ? 1.f : 0.f;
        }
        unsigned u[8];
        #pragma unroll
        for (int j = 0; j < 8; ++j)
            u[j] = xw8[((size_t)(pk[j] >> 17) * Nn + (pk[j] & 0x1FFFFu)) * 32 + sub];
        #pragma unroll
        for (int j = 0; j < 8; ++j) {
            f32x2 lo = __builtin_amdgcn_cvt_pk_f32_fp8(u[j], false);
            f32x2 hi = __builtin_amdgcn_cvt_pk_f32_fp8(u[j], true);
            a0 = fmaf(m[j], lo.x, a0);
            a1 = fmaf(m[j], lo.y, a1);
            a2 = fmaf(m[j], hi.x, a2);
            a3 = fmaf(m[j], hi.y, a3);
        }
    }
    a0 += __shfl_xor(a0, 32, 64);
    a1 += __shfl_xor(a1, 32, 64);
    a2 += __shfl_xor(a2, 32, 64);
    a3 += __shfl_xor(a3, 32, 64);
    if (half == 0) {
        float invd = 1.0f / fmaxf((float)(e - s), 1.0f);
        uint2 hv = *(const uint2*)&hb32[(size_t)w * 64 + sub * 2];
        float h0 = bflo(hv.x) + a0 * invd;
        float h1 = bfhi(hv.x) + a1 * invd;
        float h2 = bflo(hv.y) + a2 * invd;
        float h3 = bfhi(hv.y) + a3 * invd;
        uint2 o;
        o.x = (unsigned)f2bf(h0) | ((unsigned)f2bf(h1) << 16);
        o.y = (unsigned)f2bf(h2) | ((unsigned)f2bf(h3) << 16);
        *(uint2*)&hbf[(size_t)w * 64 + sub * 2] = o;
    }
}

// ---------- dual-B GEMM: hw = bf16(h@Wrel), hro = bf16(h@Wroot2 + bias2) ----------
__global__ __launch_bounds__(256, 3) void k_gemm2d(const unsigned short* __restrict__ hbf,
                                                   const unsigned short* __restrict__ WT2,
                                                   const float* __restrict__ bias2,
                                                   int Nn,
                                                   unsigned short* __restrict__ hw,
                                                   unsigned short* __restrict__ hro) {
    __shared__ __align__(16) unsigned short As[64][136];
    __shared__ __align__(16) unsigned short Bs[128][136];
    const int tid = threadIdx.x;
    const int wave = tid >> 6, lane = tid & 63;
    const int rowbase = blockIdx.x * 64;
    const int lq = lane >> 4, lr = lane & 15;

    #pragma unroll
    for (int it = 0; it < 4; ++it) {
        int c = it * 256 + tid;
        int row = c >> 4, col = c & 15;
        int rg = rowbase + row; if (rg >= Nn) rg = Nn - 1;
        *(uint4*)&As[row][col * 8] = *(const uint4*)&hbf[(size_t)rg * DH + col * 8];
    }

    for (int ph = 0; ph < 2; ++ph) {
        const unsigned short* WT = WT2 + (size_t)ph * DH * DH;
        if (ph) __syncthreads();            // prior store reads of Bs done
        #pragma unroll
        for (int it = 0; it < 8; ++it) {
            int c = it * 256 + tid;
            int row = c >> 4, col = c & 15;
            *(uint4*)&Bs[row][col * 8] = *(const uint4*)&WT[(size_t)row * DH + col * 8];
        }
        __syncthreads();                    // covers As on first iter

        f32x4 acc[8];
        #pragma unroll
        for (int nt = 0; nt < 8; ++nt) acc[nt] = (f32x4)0.f;

        #pragma unroll
        for (int ks = 0; ks < 4; ++ks) {
            const int ko = ks * 32 + lq * 8;
            bf16x8 a0 = *(const bf16x8*)&As[wave * 16 + lr][ko];
            #pragma unroll
            for (int nt = 0; nt < 8; ++nt) {
                bf16x8 bb = *(const bf16x8*)&Bs[nt * 16 + lr][ko];
                acc[nt] = __builtin_amdgcn_mfma_f32_16x16x32_bf16(a0, bb, acc[nt], 0, 0, 0);
            }
        }
        __syncthreads();                    // MFMA reads of Bs done

        // repack C-layout -> TRUE-order bf16 rows in Bs[0..63]
        float bv[8];
        #pragma unroll
        for (int nt = 0; nt < 8; ++nt) bv[nt] = ph ? bias2[nt * 16 + lr] : 0.f;
        #pragma unroll
        for (int nt = 0; nt < 8; ++nt)
            #pragma unroll
            for (int reg = 0; reg < 4; ++reg) {
                int ml = wave * 16 + lq * 4 + reg;   // own slab only
                Bs[ml][nt * 16 + lr] = f2bf(acc[nt][reg] + bv[nt]);
            }
        __syncthreads();

        unsigned short* dst = ph ? hro : hw;
        #pragma unroll
        for (int it = 0; it < 4; ++it) {
            int c = it * 256 + tid;
            int row = c >> 4, col = c & 15;
            if (rowbase + row < Nn)
                *(uint4*)&dst[(size_t)(rowbase + row) * DH + col * 8] = *(uint4*)&Bs[row][col * 8];
        }
    }
}

// ---------- final: out[w] = segsum(hw[src]) + hro[w]  (full occupancy, no LDS) ----------
__global__ __launch_bounds__(256) void k_aggout(const int* __restrict__ offsets,
                                                const unsigned* __restrict__ sorted,
                                                const uint2* __restrict__ hw2,
                                                const uint2* __restrict__ hro2,
                                                int Nn, float* __restrict__ out) {
    int w = (blockIdx.x * blockDim.x + threadIdx.x) >> 6;
    if (w >= Nn) return;
    int lane = threadIdx.x & 63;
    int half = lane >> 5, sub = lane & 31;
    int s = offsets[w], e = offsets[w + 1];
    float a0 = 0.f, a1 = 0.f, a2 = 0.f, a3 = 0.f;
    int p = s;
    for (; p + 16 <= e; p += 16) {
        unsigned pk[8];
        #pragma unroll
        for (int j = 0; j < 8; ++j) pk[j] = sorted[p + 2 * j + half];
        uint2 u[8];
        #pragma unroll
        for (int j = 0; j < 8; ++j)
            u[j] = hw2[(size_t)(pk[j] & 0x1FFFFu) * 32 + sub];
        #pragma unroll
        for (int j = 0; j < 8; ++j) {
            a0 += bflo(u[j].x); a1 += bfhi(u[j].x);
            a2 += bflo(u[j].y); a3 += bfhi(u[j].y);
        }
    }
    if (p < e) {
        unsigned pk[8]; float m[8];
        #pragma unroll
        for (int j = 0; j < 8; ++j) {
            int q = p + 2 * j + half; bool v = q < e;
            pk[j] = sorted[v ? q : e - 1];
            m[j] = v ? 1.f : 0.f;
        }
        uint2 u[8];
        #pragma unroll
        for (int j = 0; j < 8; ++j)
            u[j] = hw2[(size_t)(pk[j] & 0x1FFFFu) * 32 + sub];
        #pragma unroll
        for (int j = 0; j < 8; ++j) {
            a0 = fmaf(m[j], bflo(u[j].x), a0);
            a1 = fmaf(m[j], bfhi(u[j].x), a1);
            a2 = fmaf(m[j], bflo(u[j].y), a2);
            a3 = fmaf(m[j], bfhi(u[j].y), a3);
        }
    }
    a0 += __shfl_xor(a0, 32, 64);
    a1 += __shfl_xor(a1, 32, 64);
    a2 += __shfl_xor(a2, 32, 64);
    a3 += __shfl_xor(a3, 32, 64);
    if (half == 0) {
        uint2 hv = hro2[(size_t)w * 32 + sub];
        float4 o;
        o.x = a0 + bflo(hv.x);
        o.y = a1 + bfhi(hv.x);
        o.z = a2 + bflo(hv.y);
        o.w = a3 + bfhi(hv.y);
        *(float4*)&out[(size_t)w * DH + sub * 4] = o;
    }
}

extern "C" void kernel_launch(void* const* d_in, const int* in_sizes, int n_in,
                              void* d_out, int out_size, void* d_ws, size_t ws_size,
                              hipStream_t stream) {
    const float* x      = (const float*)d_in[0];
    const int*   eidx   = (const int*)d_in[1];
    // d_in[2] = edge_norm: unused by the reference computation
    const int*   etype  = (const int*)d_in[3];
    const float* basis  = (const float*)d_in[4];
    const float* comp   = (const float*)d_in[5];
    const float* root   = (const float*)d_in[6];
    const float* bias1  = (const float*)d_in[7];
    const float* wrel   = (const float*)d_in[8];
    const float* wroot2 = (const float*)d_in[9];
    const float* bias2  = (const float*)d_in[10];
    float* out = (float*)d_out;

    const int N = in_sizes[0] / DH;    // 40000
    const int E = in_sizes[3];         // 640000
    const int* srcA = eidx;
    const int* dstA = eidx + E;

    char* ws = (char*)d_ws;
    size_t off = 0;
    auto alloc = [&](size_t bytes) -> void* {
        void* p = (void*)(ws + off);
        off += (bytes + 255) & ~(size_t)255;
        return p;
    };
    // deg, st, ticket contiguous -> zeroed by one memset
    int* deg           = (int*)alloc((size_t)N * 4);          // N*4 multiple of 256
    unsigned long long* st = (unsigned long long*)alloc(64 * 8);   // 512 B
    int* ticket        = (int*)alloc(256);
    int* rank          = (int*)alloc((size_t)E * 4);
    int* offsets       = (int*)alloc((size_t)(N + 1) * 4);
    unsigned* sorted   = (unsigned*)alloc((size_t)E * 4);
    unsigned short* wallT = (unsigned short*)alloc((size_t)(NR + 1) * DH * DH * 2);
    unsigned short* WT2   = (unsigned short*)alloc((size_t)2 * DH * DH * 2);
    unsigned* xw8      = (unsigned*)alloc((size_t)NR * N * DH);       // fp8 e4m3
    unsigned short* hb = (unsigned short*)alloc((size_t)N * DH * 2);
    unsigned* hbf      = (unsigned*)alloc((size_t)N * (DH / 2) * 4);  // h, pi-layout bf16
    unsigned short* hw  = (unsigned short*)alloc((size_t)N * DH * 2); // h@Wrel, true order
    unsigned short* hro = (unsigned short*)alloc((size_t)N * DH * 2); // h@Wroot2+b2, true order
    (void)ws_size; (void)n_in; (void)out_size;

    hipMemsetAsync(deg, 0, (size_t)N * 4 + 768, stream);  // deg + st + ticket

    const int histB = (E + 255) / 256;              // 2500
    k_prephist<<<histB + 704, 256, 0, stream>>>(comp, basis, root, wrel, wroot2,
                                                wallT, WT2, dstA, E, deg, rank, histB);

    const int totn = N + 1;
    const int nsb = (totn + 4095) / 4096;           // 10
    k_scan<<<nsb, 1024, 0, stream>>>(deg, N, totn, offsets, st, ticket);

    const int gx = (N + 127) / 128;                 // 313 (128-row tiles)
    const int gemmB = gx * 3;                       // 939 (3 relations/block)
    const int scatB = 640;                          // 512-thr scatter blocks (interleaved)
    k_gemm1s<<<scatB + gemmB, 512, 0, stream>>>(x, wallT, bias1, N, xw8, hb,
                                                srcA, dstA, etype, E, offsets, rank, sorted,
                                                scatB, gx);

    k_agg1<<<(N * 64) / 256, 256, 0, stream>>>(offsets, sorted, xw8,
                                               (const unsigned*)hb, N, hbf);
    k_gemm2d<<<(N + 63) / 64, 256, 0, stream>>>((const unsigned short*)hbf, WT2, bias2, N, hw, hro);
    k_aggout<<<(N * 64) / 256, 256, 0, stream>>>(offsets, sorted, (const uint2*)hw,
                                                 (const uint2*)hro, N, out);
}